// Round 1
// baseline (111.687 us; speedup 1.0000x reference)
//
#include <hip/hip_runtime.h>
#include <hip/hip_bf16.h>
#include <stdint.h>

#define N2 8192
#define D 256
#define DB 512          // bytes per bf16 row
#define RB_ROWS 256     // rows per block (4 waves x 64)
#define WAVE_ROWS 64
#define CHUNK 32        // cols staged per iteration
#define JSPLIT 16
#define COLS_PER_BLOCK (N2 / JSPLIT)          // 512
#define CHUNKS_PER_BLOCK (COLS_PER_BLOCK / CHUNK) // 16

using short8 = __attribute__((ext_vector_type(8))) short;
using f32x4  = __attribute__((ext_vector_type(4))) float;

__device__ inline unsigned short f2bf(float x) {
    union { float f; uint32_t u; } a; a.f = x;
    uint32_t r = (a.u + 0x7fff + ((a.u >> 16) & 1)) >> 16;  // RNE
    return (unsigned short)r;
}

// ---------------- kernel 1: interleave + L2-normalize + bf16 ----------------
__global__ void knorm(const float* __restrict__ z1, const float* __restrict__ z2,
                      unsigned short* __restrict__ Zb, float* __restrict__ den) {
    int tid  = threadIdx.x;
    int lane = tid & 63;
    int w    = tid >> 6;
    int row  = blockIdx.x * 4 + w;          // 0..8191
    const float* src = (row & 1) ? z2 : z1;
    int srow = row >> 1;
    float4 v = reinterpret_cast<const float4*>(src + (size_t)srow * D)[lane];
    float ss = v.x*v.x + v.y*v.y + v.z*v.z + v.w*v.w;
    #pragma unroll
    for (int off = 1; off < 64; off <<= 1) ss += __shfl_xor(ss, off);
    float inv = rsqrtf(ss);                  // norm > 0 for gaussian data
    ushort4 o;
    o.x = f2bf(v.x * inv); o.y = f2bf(v.y * inv);
    o.z = f2bf(v.z * inv); o.w = f2bf(v.w * inv);
    *reinterpret_cast<ushort4*>(Zb + (size_t)row * D + lane * 4) = o;

    int gid = blockIdx.x * blockDim.x + tid;
    if (gid < N2) den[gid] = 0.f;
}

// ---------------- kernel 2: S rowsums (excl diag) + positive dots -----------
__launch_bounds__(256, 2)
__global__ void kmain(const unsigned short* __restrict__ Zb,
                      float* __restrict__ den, float* __restrict__ pos) {
    __shared__ char tile[CHUNK * DB];        // 16 KB, XOR-swizzled rows
    int tid  = threadIdx.x;
    int lane = tid & 63;
    int w    = tid >> 6;
    int bid  = blockIdx.x;
    int rb   = bid & 31;                     // 32 row-blocks
    int js   = bid >> 5;                     // 16 column splits
    int Rw   = rb * RB_ROWS + w * WAVE_ROWS; // wave's 64-row base
    int Cbase = js * COLS_PER_BLOCK;
    int l15 = lane & 15, g = lane >> 4;

    const char* Zc = reinterpret_cast<const char*>(Zb);

    // A fragments: 4 m-frags (16 rows each) x 8 k-steps, all in registers.
    // mfma_16x16x32_bf16 A layout: lane l -> row l&15, k = (l>>4)*8 + j
    short8 A[4][8];
    #pragma unroll
    for (int mf = 0; mf < 4; ++mf) {
        const char* rowp = Zc + (size_t)(Rw + mf*16 + l15) * DB + g*16;
        #pragma unroll
        for (int s = 0; s < 8; ++s)
            A[mf][s] = *reinterpret_cast<const short8*>(rowp + s*64);
    }

    f32x4 acc[4][2];
    float rsum[4][4];
    #pragma unroll
    for (int mf = 0; mf < 4; ++mf) {
        #pragma unroll
        for (int r = 0; r < 4; ++r) rsum[mf][r] = 0.f;
        #pragma unroll
        for (int nf = 0; nf < 2; ++nf) acc[mf][nf] = (f32x4){0.f,0.f,0.f,0.f};
    }

    for (int c = 0; c < CHUNKS_PER_BLOCK; ++c) {
        int C0 = Cbase + c * CHUNK;
        __syncthreads();                     // protect tile from prev readers
        // stage 32 Z-rows (16 KB) into LDS, swizzled: byte ^= (row&7)<<4
        #pragma unroll
        for (int i = 0; i < 4; ++i) {
            int q  = tid + 256 * i;          // 0..1023 16B-chunks
            int r  = q >> 5;
            int cb = (q & 31) * 16;
            uint4 v = *reinterpret_cast<const uint4*>(Zc + (size_t)(C0 + r) * DB + cb);
            *reinterpret_cast<uint4*>(&tile[r * DB + (cb ^ ((r & 7) << 4))]) = v;
        }
        __syncthreads();

        #pragma unroll
        for (int s = 0; s < 8; ++s) {
            int cb = s*64 + g*16;
            int r0 = l15, r1 = 16 + l15;
            short8 B0 = *reinterpret_cast<const short8*>(&tile[r0 * DB + (cb ^ ((r0 & 7) << 4))]);
            short8 B1 = *reinterpret_cast<const short8*>(&tile[r1 * DB + (cb ^ ((r1 & 7) << 4))]);
            #pragma unroll
            for (int mf = 0; mf < 4; ++mf) {
                acc[mf][0] = __builtin_amdgcn_mfma_f32_16x16x32_bf16(A[mf][s], B0, acc[mf][0], 0, 0, 0);
                acc[mf][1] = __builtin_amdgcn_mfma_f32_16x16x32_bf16(A[mf][s], B1, acc[mf][1], 0, 0, 0);
            }
        }

        // epilogue: e = exp(2*dot); diag skip + pos capture only on diag tiles
        #pragma unroll
        for (int mf = 0; mf < 4; ++mf) {
            int Rt = Rw + mf * 16;
            #pragma unroll
            for (int nf = 0; nf < 2; ++nf) {
                int Ct = C0 + nf * 16;
                bool dg = (Ct == Rt);
                #pragma unroll
                for (int r = 0; r < 4; ++r) {
                    float v = acc[mf][nf][r];     // C layout: row g*4+r, col l15
                    float e = __expf(v + v);
                    if (dg) {
                        int rl = g * 4 + r;
                        if (l15 == rl) e = 0.f;            // exclude diagonal
                        if (l15 == (rl ^ 1)) pos[Rt + rl] = v;  // positive dot
                    }
                    rsum[mf][r] += e;
                    acc[mf][nf][r] = 0.f;
                }
            }
        }
    }

    // reduce rowsums across the 16 columns (lanes sharing g) and accumulate
    #pragma unroll
    for (int mf = 0; mf < 4; ++mf) {
        #pragma unroll
        for (int r = 0; r < 4; ++r) {
            float v = rsum[mf][r];
            v += __shfl_xor(v, 1); v += __shfl_xor(v, 2);
            v += __shfl_xor(v, 4); v += __shfl_xor(v, 8);
            if (l15 == 0) atomicAdd(&den[Rw + mf*16 + g*4 + r], v);
        }
    }
}

// ---------------- kernel 3: loss reduce -------------------------------------
__global__ void kloss(const float* __restrict__ den, const float* __restrict__ pos,
                      float* __restrict__ out) {
    __shared__ float red[4];
    int t = threadIdx.x;
    float s = 0.f;
    for (int i = t; i < N2; i += 256)
        s += logf(den[i] + 1e-8f) - 2.f * pos[i];
    #pragma unroll
    for (int off = 1; off < 64; off <<= 1) s += __shfl_xor(s, off);
    if ((t & 63) == 0) red[t >> 6] = s;
    __syncthreads();
    if (t == 0) out[0] = (red[0] + red[1] + red[2] + red[3]) * (1.f / (float)N2);
}

extern "C" void kernel_launch(void* const* d_in, const int* in_sizes, int n_in,
                              void* d_out, int out_size, void* d_ws, size_t ws_size,
                              hipStream_t stream) {
    const float* z1 = (const float*)d_in[0];
    const float* z2 = (const float*)d_in[1];
    char* ws = (char*)d_ws;
    unsigned short* Zb = (unsigned short*)ws;                       // 4 MB bf16 Z
    float* den = (float*)(ws + (size_t)N2 * DB);                    // 32 KB
    float* pos = (float*)(ws + (size_t)N2 * DB + (size_t)N2 * 4);   // 32 KB

    knorm<<<N2 / 4, 256, 0, stream>>>(z1, z2, Zb, den);
    kmain<<<32 * JSPLIT, 256, 0, stream>>>(Zb, den, pos);
    kloss<<<1, 256, 0, stream>>>(den, pos, (float*)d_out);
}

// Round 2
// 104.459 us; speedup vs baseline: 1.0692x; 1.0692x over previous
//
#include <hip/hip_runtime.h>
#include <hip/hip_bf16.h>
#include <stdint.h>

#define N2 8192
#define D 256
#define DB 512          // bytes per bf16 row
#define RB_ROWS 256     // rows per block (8 waves x 32)
#define WAVE_ROWS 32
#define CHUNK 32        // cols staged per iteration
#define JSPLIT 16
#define COLS_PER_BLOCK (N2 / JSPLIT)              // 512
#define CHUNKS_PER_BLOCK (COLS_PER_BLOCK / CHUNK) // 16
#define SWZ(r, b) ((b) ^ (((r) & 7) << 4))

using short8 = __attribute__((ext_vector_type(8))) short;
using f32x4  = __attribute__((ext_vector_type(4))) float;

typedef __attribute__((address_space(1))) const char gchar_t;
typedef __attribute__((address_space(3))) char       lchar_t;

__device__ inline unsigned short f2bf(float x) {
    union { float f; uint32_t u; } a; a.f = x;
    uint32_t r = (a.u + 0x7fff + ((a.u >> 16) & 1)) >> 16;  // RNE
    return (unsigned short)r;
}

// ---------------- kernel 1: interleave + L2-normalize + bf16 ----------------
__global__ void knorm(const float* __restrict__ z1, const float* __restrict__ z2,
                      unsigned short* __restrict__ Zb, float* __restrict__ den) {
    int tid  = threadIdx.x;
    int lane = tid & 63;
    int w    = tid >> 6;
    int row  = blockIdx.x * 4 + w;          // 0..8191
    const float* src = (row & 1) ? z2 : z1;
    int srow = row >> 1;
    float4 v = reinterpret_cast<const float4*>(src + (size_t)srow * D)[lane];
    float ss = v.x*v.x + v.y*v.y + v.z*v.z + v.w*v.w;
    #pragma unroll
    for (int off = 1; off < 64; off <<= 1) ss += __shfl_xor(ss, off);
    float inv = rsqrtf(ss);
    ushort4 o;
    o.x = f2bf(v.x * inv); o.y = f2bf(v.y * inv);
    o.z = f2bf(v.z * inv); o.w = f2bf(v.w * inv);
    *reinterpret_cast<ushort4*>(Zb + (size_t)row * D + lane * 4) = o;

    int gid = blockIdx.x * blockDim.x + tid;
    if (gid < N2) den[gid] = 0.f;
}

// ---------------- kernel 2: S rowsums (excl diag) + positive dots -----------
__launch_bounds__(512, 4)
__global__ void kmain(const unsigned short* __restrict__ Zb,
                      float* __restrict__ den, float* __restrict__ pos) {
    __shared__ char tile[2][CHUNK * DB];     // 2 x 16 KB double buffer
    int tid  = threadIdx.x;
    int lane = tid & 63;
    int w    = tid >> 6;                     // 0..7
    int bid  = blockIdx.x;
    int rb   = bid & 31;                     // 32 row-blocks
    int js   = bid >> 5;                     // 16 column splits
    int Rw   = rb * RB_ROWS + w * WAVE_ROWS; // wave's 32-row base
    int Cbase = js * COLS_PER_BLOCK;
    int l15 = lane & 15, g = lane >> 4;

    const char* Zc = reinterpret_cast<const char*>(Zb);

    // A fragments: 2 m-frags (16 rows) x 8 k-steps, register-resident (64 VGPR)
    short8 A[2][8];
    #pragma unroll
    for (int mf = 0; mf < 2; ++mf) {
        const char* rowp = Zc + (size_t)(Rw + mf*16 + l15) * DB + g*16;
        #pragma unroll
        for (int s = 0; s < 8; ++s)
            A[mf][s] = *reinterpret_cast<const short8*>(rowp + s*64);
    }

    // staging geometry: wave stages 4 rows (w*4 .. w*4+3) via 2 DMA ops;
    // source is pre-swizzled so linear LDS dest yields swizzled layout.
    int soff[2];
    #pragma unroll
    for (int k = 0; k < 2; ++k) {
        int r = w*4 + k*2 + (lane >> 5);     // local row 0..31
        int y = (lane & 31) * 16;
        soff[k] = r * DB + SWZ(r, y);
    }

    float rsum[2][4];
    #pragma unroll
    for (int mf = 0; mf < 2; ++mf)
        #pragma unroll
        for (int r = 0; r < 4; ++r) rsum[mf][r] = 0.f;

    const size_t cb0 = (size_t)Cbase * DB;

    #define STAGE(bf, coff)                                                          \
        __builtin_amdgcn_global_load_lds(                                            \
            (gchar_t*)(Zc + (coff) + soff[0]),                                       \
            (lchar_t*)(&tile[bf][(w*4 + 0) * DB]), 16, 0, 0);                        \
        __builtin_amdgcn_global_load_lds(                                            \
            (gchar_t*)(Zc + (coff) + soff[1]),                                       \
            (lchar_t*)(&tile[bf][(w*4 + 2) * DB]), 16, 0, 0);

    STAGE(0, cb0);                           // prologue: chunk 0 -> buf 0
    int buf = 0;

    for (int c = 0; c < CHUNKS_PER_BLOCK; ++c) {
        if (c + 1 < CHUNKS_PER_BLOCK) {
            STAGE(buf ^ 1, cb0 + (size_t)(c + 1) * CHUNK * DB);
            asm volatile("s_waitcnt vmcnt(2)" ::: "memory");   // cur buf done, next 2 in flight
        } else {
            asm volatile("s_waitcnt vmcnt(0)" ::: "memory");
        }
        __builtin_amdgcn_s_barrier();
        __builtin_amdgcn_sched_barrier(0);

        f32x4 acc[2][2];
        #pragma unroll
        for (int mf = 0; mf < 2; ++mf)
            #pragma unroll
            for (int nf = 0; nf < 2; ++nf) acc[mf][nf] = (f32x4){0.f,0.f,0.f,0.f};

        #pragma unroll
        for (int s = 0; s < 8; ++s) {
            int cb = s*64 + g*16;
            int r0 = l15, r1 = 16 + l15;
            short8 B0 = *reinterpret_cast<const short8*>(&tile[buf][r0 * DB + SWZ(r0, cb)]);
            short8 B1 = *reinterpret_cast<const short8*>(&tile[buf][r1 * DB + SWZ(r1, cb)]);
            #pragma unroll
            for (int mf = 0; mf < 2; ++mf) {
                acc[mf][0] = __builtin_amdgcn_mfma_f32_16x16x32_bf16(A[mf][s], B0, acc[mf][0], 0, 0, 0);
                acc[mf][1] = __builtin_amdgcn_mfma_f32_16x16x32_bf16(A[mf][s], B1, acc[mf][1], 0, 0, 0);
            }
        }

        int C0 = Cbase + c * CHUNK;
        #pragma unroll
        for (int mf = 0; mf < 2; ++mf) {
            int Rt = Rw + mf * 16;
            #pragma unroll
            for (int nf = 0; nf < 2; ++nf) {
                int Ct = C0 + nf * 16;
                bool dg = (Ct == Rt);
                #pragma unroll
                for (int r = 0; r < 4; ++r) {
                    float v = acc[mf][nf][r];            // C: row g*4+r, col l15
                    float e = exp2f(v * 2.885390081777927f);  // exp(2v)
                    if (dg) {
                        int rl = g * 4 + r;
                        if (l15 == rl) e = 0.f;                 // exclude diagonal
                        if (l15 == (rl ^ 1)) pos[Rt + rl] = v;  // positive dot
                    }
                    rsum[mf][r] += e;
                }
            }
        }
        __builtin_amdgcn_sched_barrier(0);
        __builtin_amdgcn_s_barrier();        // readers done before next STAGE overwrites
        buf ^= 1;
    }

    // reduce rowsums across the 16 cols held per lane-group, then accumulate
    #pragma unroll
    for (int mf = 0; mf < 2; ++mf) {
        #pragma unroll
        for (int r = 0; r < 4; ++r) {
            float v = rsum[mf][r];
            v += __shfl_xor(v, 1); v += __shfl_xor(v, 2);
            v += __shfl_xor(v, 4); v += __shfl_xor(v, 8);
            if (l15 == 0) atomicAdd(&den[Rw + mf*16 + g*4 + r], v);
        }
    }
}

// ---------------- kernel 3: loss reduce -------------------------------------
__global__ void kloss(const float* __restrict__ den, const float* __restrict__ pos,
                      float* __restrict__ out) {
    __shared__ float red[4];
    int tid = threadIdx.x;
    int idx = blockIdx.x * 256 + tid;
    float s = logf(den[idx] + 1e-8f) - 2.f * pos[idx];
    #pragma unroll
    for (int off = 1; off < 64; off <<= 1) s += __shfl_xor(s, off);
    if ((tid & 63) == 0) red[tid >> 6] = s;
    __syncthreads();
    if (tid == 0)
        atomicAdd(out, (red[0] + red[1] + red[2] + red[3]) * (1.f / (float)N2));
}

extern "C" void kernel_launch(void* const* d_in, const int* in_sizes, int n_in,
                              void* d_out, int out_size, void* d_ws, size_t ws_size,
                              hipStream_t stream) {
    const float* z1 = (const float*)d_in[0];
    const float* z2 = (const float*)d_in[1];
    char* ws = (char*)d_ws;
    unsigned short* Zb = (unsigned short*)ws;                       // 4 MB bf16 Z
    float* den = (float*)(ws + (size_t)N2 * DB);                    // 32 KB
    float* pos = (float*)(ws + (size_t)N2 * DB + (size_t)N2 * 4);   // 32 KB

    hipMemsetAsync(d_out, 0, sizeof(float), stream);
    knorm<<<N2 / 4, 256, 0, stream>>>(z1, z2, Zb, den);
    kmain<<<32 * JSPLIT, 512, 0, stream>>>(Zb, den, pos);
    kloss<<<N2 / 256, 256, 0, stream>>>(den, pos, (float*)d_out);
}